// Round 3
// baseline (179.339 us; speedup 1.0000x reference)
//
#include <hip/hip_runtime.h>
#include <hip/hip_bf16.h>
#include <stdint.h>

typedef __attribute__((ext_vector_type(8))) short short8;
typedef __attribute__((ext_vector_type(4))) float f32x4;

#define NCHUNK 15625   // 500000 / 32 rows per chunk (exact)
#define NBLK 256
#define NTHR 512
#define NWAVE_TOT (NBLK * 8)
#define LDS_T 12       // m-tiles (of 16) whose W2 frags live in LDS; rest via VMEM
#define LDS_BYTES (LDS_T * 8 * 64 * 16)   // 12 t * 8 s * 64 lanes * 16 B = 98304

// round-to-nearest-even fp32 -> bf16 bits (prep only)
__device__ __forceinline__ unsigned short f2bf(float f) {
    unsigned int u = __float_as_uint(f);
    u = (u + 0x7fffu + ((u >> 16) & 1u)) >> 16;
    return (unsigned short)u;
}

// packed pair convert: {lo:[15:0], hi:[31:16]} bf16, RNE
__device__ __forceinline__ uint32_t cvtpk(float lo, float hi) {
    uint32_t r;
    asm("v_cvt_pk_bf16_f32 %0, %1, %2" : "=v"(r) : "v"(lo), "v"(hi));
    return r;
}

// Pack W2 into mfma_f32_16x16x32_bf16 fragment order (verified in round 2):
//   frag f = s*16 + t; lane l holds W2[k = s*32 + (l>>4)*8 + j][n = t*16 + (l&15)]
// Under the operand swap this same fragment serves as A = W2^T (m = l&15 = col-of-W2).
// Also pack W1+b1 -> [256] float4 {W1[0][k],W1[1][k],W1[2][k],b1[k]}
// and  W3+b2 -> [256] float4 {W3[c][0],W3[c][1],W3[c][2],b2[c]} (w unused in fused)
__global__ void prep_kernel(const float* __restrict__ W1, const float* __restrict__ b1,
                            const float* __restrict__ W2, const float* __restrict__ b2,
                            const float* __restrict__ W3,
                            uint4* __restrict__ w2p, float4* __restrict__ w1b1,
                            float4* __restrict__ w3b2) {
    int id = blockIdx.x * 256 + threadIdx.x;
    if (id < 8192) {
        int lane = id & 63;
        int f = id >> 6;
        int s = f >> 4, t = f & 15;
        int g = lane >> 4, c = lane & 15;
        int n = t * 16 + c;
        int kbase = s * 32 + g * 8;
        unsigned int w[4];
#pragma unroll
        for (int jj = 0; jj < 4; ++jj) {
            unsigned int lo = f2bf(W2[(kbase + 2 * jj) * 256 + n]);
            unsigned int hi = f2bf(W2[(kbase + 2 * jj + 1) * 256 + n]);
            w[jj] = lo | (hi << 16);
        }
        w2p[id] = make_uint4(w[0], w[1], w[2], w[3]);
    } else if (id < 8448) {
        int k = id - 8192;
        w1b1[k] = make_float4(W1[k], W1[256 + k], W1[512 + k], b1[k]);
    } else if (id < 8704) {
        int c2 = id - 8448;
        w3b2[c2] = make_float4(W3[c2 * 3 + 0], W3[c2 * 3 + 1], W3[c2 * 3 + 2], b2[c2]);
    }
}

__global__ __launch_bounds__(NTHR, 2) void fused_kernel(
    const float* __restrict__ x, const uint4* __restrict__ w2p,
    const float4* __restrict__ w1b1, const float4* __restrict__ w3b2,
    const float* __restrict__ b2, const float* __restrict__ b3,
    float* __restrict__ out)
{
    extern __shared__ char smem[];   // 96 KB: W2 frags for t = 0..LDS_T-1
    const int tid = threadIdx.x;
    const int lane = tid & 63;
    const int g = lane >> 4;         // k-group / butterfly group
    const int lr = lane & 15;        // batch row within 16-row n-tile

    // one-time stage of LDS-resident W2 frags (linear coalesced dwordx4)
    {
        uint4* ls = (uint4*)smem;
#pragma unroll
        for (int it = 0; it < LDS_T; ++it) {
            int idx = it * NTHR + tid;           // 12*512 = 6144 uint4 = 96 KB
            int lane2 = idx & 63;
            int f2 = idx >> 6;                   // 0..95 = s*LDS_T + t
            int s2 = f2 / LDS_T, t2 = f2 % LDS_T;
            ls[idx] = w2p[(s2 * 16 + t2) * 64 + lane2];
        }
    }
    __syncthreads();   // LDS read-only afterwards; waves fully independent

    const float b30 = b3[0], b31 = b3[1], b32 = b3[2];
    const short8* afr = (const short8*)smem;
    const int gwave = blockIdx.x * 8 + (tid >> 6);

    for (int chunk = gwave; chunk < NCHUNK; chunk += NWAVE_TOT) {
        const int row0 = chunk * 32;

        // ---- bond lengths for this lane's 2 batch rows (lr, lr+16) ----
        float q0[2], q1[2], q2[2];
#pragma unroll
        for (int nt = 0; nt < 2; ++nt) {
            const float* xp = x + (long)(row0 + nt * 16 + lr) * 9;
            float d0 = xp[0] - xp[3], d1 = xp[1] - xp[4], d2 = xp[2] - xp[5];
            float e0 = xp[0] - xp[6], e1 = xp[1] - xp[7], e2 = xp[2] - xp[8];
            float f0 = xp[3] - xp[6], f1 = xp[4] - xp[7], f2 = xp[5] - xp[8];
            q0[nt] = sqrtf(d0 * d0 + d1 * d1 + d2 * d2);
            q1[nt] = sqrtf(e0 * e0 + e1 * e1 + e2 * e2);
            q2[nt] = sqrtf(f0 * f0 + f1 * f1 + f2 * f2);
        }

        // ---- acc init = b2 (so layer-3 skips the bias add; relu sees h+b2) ----
        // C layout: lane holds h2[batch row = nt*16 + lr][c = t*16 + g*4 + r]
        f32x4 acc[16][2];
#pragma unroll
        for (int t = 0; t < 16; ++t) {
            float4 bv = *(const float4*)(b2 + t * 16 + g * 4);   // 16B-aligned
            f32x4 bi; bi[0] = bv.x; bi[1] = bv.y; bi[2] = bv.z; bi[3] = bv.w;
            acc[t][0] = bi; acc[t][1] = bi;
        }

        // ---- K loop: build h1 B-frags on the fly; A = W2^T frags (LDS + VMEM) ----
#pragma unroll 1
        for (int s = 0; s < 8; ++s) {
            // issue VMEM frag loads early (t = 12..15), coalesced 1KB/instr, L1/L2-hot
            uint4 fv[4];
#pragma unroll
            for (int tv = 0; tv < 4; ++tv)
                fv[tv] = w2p[(s * 16 + LDS_T + tv) * 64 + lane];

            // layer-1: h1[row][k] for k = s*32 + g*8 + j, rows lr and lr+16
            union { short8 s8; uint32_t u[4]; } pk0, pk1;
#pragma unroll
            for (int jj = 0; jj < 4; ++jj) {
                float4 wa = w1b1[s * 32 + g * 8 + 2 * jj];
                float4 wb = w1b1[s * 32 + g * 8 + 2 * jj + 1];
                float h0a = fmaf(q0[0], wa.x, fmaf(q1[0], wa.y, fmaf(q2[0], wa.z, wa.w)));
                float h0b = fmaf(q0[0], wb.x, fmaf(q1[0], wb.y, fmaf(q2[0], wb.z, wb.w)));
                float h1a = fmaf(q0[1], wa.x, fmaf(q1[1], wa.y, fmaf(q2[1], wa.z, wa.w)));
                float h1b = fmaf(q0[1], wb.x, fmaf(q1[1], wb.y, fmaf(q2[1], wb.z, wb.w)));
                pk0.u[jj] = cvtpk(fmaxf(h0a, 0.0f), fmaxf(h0b, 0.0f));
                pk1.u[jj] = cvtpk(fmaxf(h1a, 0.0f), fmaxf(h1b, 0.0f));
            }
            const short8 bv0 = pk0.s8, bv1 = pk1.s8;

#pragma unroll
            for (int t = 0; t < LDS_T; ++t) {
                short8 av = afr[(s * LDS_T + t) * 64 + lane];
                acc[t][0] = __builtin_amdgcn_mfma_f32_16x16x32_bf16(av, bv0, acc[t][0], 0, 0, 0);
                acc[t][1] = __builtin_amdgcn_mfma_f32_16x16x32_bf16(av, bv1, acc[t][1], 0, 0, 0);
            }
#pragma unroll
            for (int tv = 0; tv < 4; ++tv) {
                union { uint4 q; short8 s8; } cvt; cvt.q = fv[tv];
                acc[LDS_T + tv][0] = __builtin_amdgcn_mfma_f32_16x16x32_bf16(cvt.s8, bv0, acc[LDS_T + tv][0], 0, 0, 0);
                acc[LDS_T + tv][1] = __builtin_amdgcn_mfma_f32_16x16x32_bf16(cvt.s8, bv1, acc[LDS_T + tv][1], 0, 0, 0);
            }
        }

        // ---- layer 3: in-register partial dot over this lane's 64 columns ----
        float p00 = 0.f, p01 = 0.f, p02 = 0.f;   // row lr      (nt=0)
        float p10 = 0.f, p11 = 0.f, p12 = 0.f;   // row lr+16   (nt=1)
#pragma unroll
        for (int t = 0; t < 16; ++t) {
#pragma unroll
            for (int r = 0; r < 4; ++r) {
                float4 w3 = w3b2[t * 16 + g * 4 + r];   // L1-hot, aligned
                float v0 = fmaxf(acc[t][0][r], 0.0f);
                float v1 = fmaxf(acc[t][1][r], 0.0f);
                p00 = fmaf(v0, w3.x, p00); p01 = fmaf(v0, w3.y, p01); p02 = fmaf(v0, w3.z, p02);
                p10 = fmaf(v1, w3.x, p10); p11 = fmaf(v1, w3.y, p11); p12 = fmaf(v1, w3.z, p12);
            }
        }

        // ---- reduce over the 4 k-groups (lanes lr, lr+16, lr+32, lr+48) ----
#pragma unroll
        for (int i = 0; i < 1; ++i) { } // (keep structure flat)
        p00 += __shfl_xor(p00, 16, 64); p00 += __shfl_xor(p00, 32, 64);
        p01 += __shfl_xor(p01, 16, 64); p01 += __shfl_xor(p01, 32, 64);
        p02 += __shfl_xor(p02, 16, 64); p02 += __shfl_xor(p02, 32, 64);
        p10 += __shfl_xor(p10, 16, 64); p10 += __shfl_xor(p10, 32, 64);
        p11 += __shfl_xor(p11, 16, 64); p11 += __shfl_xor(p11, 32, 64);
        p12 += __shfl_xor(p12, 16, 64); p12 += __shfl_xor(p12, 32, 64);

        // ---- eigenvalues + store: g==0 stores nt=0 rows, g==1 stores nt=1 rows ----
        if (g < 2) {
            float w0 = (g == 0 ? p00 : p10) + b30;
            float w1v = (g == 0 ? p01 : p11) + b31;
            float wc = (g == 0 ? p02 : p12) + b32;
            float mm = 0.5f * (w0 + w1v);
            float dd = 0.5f * (w0 - w1v);
            float rad = sqrtf(fmaf(dd, dd, wc * wc));
            int row = row0 + g * 16 + lr;
            float2 o = make_float2(mm - rad, mm + rad);
            *(float2*)(out + (long)row * 2) = o;
        }
    }
}

extern "C" void kernel_launch(void* const* d_in, const int* in_sizes, int n_in,
                              void* d_out, int out_size, void* d_ws, size_t ws_size,
                              hipStream_t stream) {
    const float* x  = (const float*)d_in[0];
    const float* W1 = (const float*)d_in[1];
    const float* b1 = (const float*)d_in[2];
    const float* W2 = (const float*)d_in[3];
    const float* b2 = (const float*)d_in[4];
    const float* W3 = (const float*)d_in[5];
    const float* b3 = (const float*)d_in[6];
    float* out = (float*)d_out;

    char* ws = (char*)d_ws;
    uint4*  w2p  = (uint4*)ws;                 // 131072 B: packed bf16 W2 fragments
    float4* w1b1 = (float4*)(ws + 131072);     // 4096 B
    float4* w3b2 = (float4*)(ws + 135168);     // 4096 B

    // allow 96 KB dynamic LDS (not a stream op; capture-safe)
    (void)hipFuncSetAttribute((const void*)fused_kernel,
                              hipFuncAttributeMaxDynamicSharedMemorySize, LDS_BYTES);

    prep_kernel<<<34, 256, 0, stream>>>(W1, b1, W2, b2, W3, w2p, w1b1, w3b2);
    fused_kernel<<<NBLK, NTHR, LDS_BYTES, stream>>>(x, w2p, w1b1, w3b2, b2, b3, out);
}